// Round 1
// baseline (1422.715 us; speedup 1.0000x reference)
//
#include <hip/hip_runtime.h>
#include <math.h>

#define DIMX 50
#define KK   51
#define NE   6
#define NB   8
#define NVOX ((size_t)NB * NE * DIMX * DIMX * DIMX)  // 6,000,000

// ---------------- taps: per-element 1D Gaussian + global-sum scale ----------------
__global__ void taps_kernel(const float* __restrict__ sigma,
                            float* __restrict__ g,   // E*51 raw 1D gaussian
                            float* __restrict__ gs,  // E*51 scaled (a_e/S folded in)
                            float* __restrict__ maxval) {
    __shared__ float sg[NE * KK];
    __shared__ float ssum[NE];
    int t = threadIdx.x;
    if (t == 0) *maxval = 0.f;
    if (t < NE * KK) {
        int e = t / KK, i = t % KK;
        float d = (float)i - 25.0f;
        float var = sigma[e] * sigma[e];
        float val = expf(-d * d / (2.f * var));
        sg[t] = val;
        g[t] = val;
    }
    __syncthreads();
    if (t < NE) {
        float s = 0.f;
        for (int i = 0; i < KK; ++i) s += sg[t * KK + i];
        ssum[t] = s;
    }
    __syncthreads();
    if (t < NE * KK) {
        int e = t / KK;
        float S = 0.f;
        for (int e2 = 0; e2 < NE; ++e2) {
            float var2 = sigma[e2] * sigma[e2];
            float a2 = 1.f / (2.f * (float)M_PI * var2);
            float se = ssum[e2];
            S += a2 * se * se * se;
        }
        float var = sigma[e] * sigma[e];
        float a = 1.f / (2.f * (float)M_PI * var);
        gs[t] = sg[t] * (a / S);
    }
}

// ---------------- separable blur pass (zero padding 25) ----------------
template <int STRIDE>
__global__ void blur_pass(const float* __restrict__ in, float* __restrict__ out,
                          const float* __restrict__ taps) {
    __shared__ float st[NE * KK];
    for (int i = threadIdx.x; i < NE * KK; i += blockDim.x) st[i] = taps[i];
    __syncthreads();
    size_t idx = (size_t)blockIdx.x * blockDim.x + threadIdx.x;
    if (idx >= NVOX) return;
    int w = (int)(idx % DIMX);
    int h = (int)((idx / DIMX) % DIMX);
    int d = (int)((idx / (DIMX * DIMX)) % DIMX);
    int e = (int)((idx / (DIMX * DIMX * DIMX)) % NE);
    int pos = (STRIDE == 1) ? w : (STRIDE == DIMX ? h : d);
    const float* tp = &st[e * KK];
    int jlo = 25 - pos; if (jlo < 0) jlo = 0;
    int jhi = 75 - pos; if (jhi > KK) jhi = KK;
    float acc = 0.f;
    const float* p = in + (long)idx + (long)(jlo - 25) * STRIDE;
    for (int j = jlo; j < jhi; ++j, p += STRIDE) acc = fmaf(tp[j], *p, acc);
    out[idx] = acc;
}

// ---------------- global max (all values >= 0) ----------------
__global__ void max_reduce(const float* __restrict__ in, float* __restrict__ maxval) {
    size_t stride = (size_t)gridDim.x * blockDim.x;
    float m = 0.f;
    for (size_t i = (size_t)blockIdx.x * blockDim.x + threadIdx.x; i < NVOX; i += stride)
        m = fmaxf(m, in[i]);
    for (int o = 32; o; o >>= 1) m = fmaxf(m, __shfl_xor(m, o));
    if ((threadIdx.x & 63) == 0) atomicMax((int*)maxval, __float_as_int(m));
}

// ---------------- fused conv3x3x3(VALID) + bias + maxpool2 + relu ----------------
// One thread = one pooled output voxel. DIV: divide by *maxval before bias (conv1).
template <int CIN, int DIN, int DP, bool DIV>
__global__ void conv_pool_relu(const float* __restrict__ in, const float* __restrict__ w,
                               const float* __restrict__ bias, const float* __restrict__ maxval,
                               float* __restrict__ out, int COUT) {
    constexpr int DP3 = DP * DP * DP;
    const int co = blockIdx.y, b = blockIdx.z;
    __shared__ float sw[CIN * 27];
    for (int i = threadIdx.x; i < CIN * 27; i += blockDim.x)
        sw[i] = w[(size_t)co * CIN * 27 + i];
    __syncthreads();
    int p = blockIdx.x * blockDim.x + threadIdx.x;
    if (p >= DP3) return;
    int px = p % DP, py = (p / DP) % DP, pz = p / (DP * DP);
    int x0 = 2 * px, y0 = 2 * py, z0 = 2 * pz;
    const float* ib = in + (size_t)b * CIN * DIN * DIN * DIN;
    float acc[8];
#pragma unroll
    for (int i = 0; i < 8; ++i) acc[i] = 0.f;
    for (int ci = 0; ci < CIN; ++ci) {
        float win[4][4][4];
        const float* cb = ib + (size_t)ci * DIN * DIN * DIN + ((z0 * DIN + y0) * DIN + x0);
#pragma unroll
        for (int dz = 0; dz < 4; ++dz)
#pragma unroll
            for (int dy = 0; dy < 4; ++dy) {
                const float* r = cb + (dz * DIN + dy) * DIN;
                if constexpr ((DIN & 1) == 0) {
                    float2 v0 = *(const float2*)(r);
                    float2 v1 = *(const float2*)(r + 2);
                    win[dz][dy][0] = v0.x; win[dz][dy][1] = v0.y;
                    win[dz][dy][2] = v1.x; win[dz][dy][3] = v1.y;
                } else {
#pragma unroll
                    for (int dx = 0; dx < 4; ++dx) win[dz][dy][dx] = r[dx];
                }
            }
        const float* wc = &sw[ci * 27];
#pragma unroll
        for (int kz = 0; kz < 3; ++kz)
#pragma unroll
            for (int ky = 0; ky < 3; ++ky)
#pragma unroll
                for (int kx = 0; kx < 3; ++kx) {
                    float wv = wc[(kz * 3 + ky) * 3 + kx];
#pragma unroll
                    for (int oz = 0; oz < 2; ++oz)
#pragma unroll
                        for (int oy = 0; oy < 2; ++oy)
#pragma unroll
                            for (int ox = 0; ox < 2; ++ox)
                                acc[(oz * 2 + oy) * 2 + ox] =
                                    fmaf(wv, win[oz + kz][oy + ky][ox + kx],
                                         acc[(oz * 2 + oy) * 2 + ox]);
                }
    }
    float m = acc[0];
#pragma unroll
    for (int i = 1; i < 8; ++i) m = fmaxf(m, acc[i]);
    float o;
    if constexpr (DIV) o = m / (*maxval) + bias[co];
    else               o = m + bias[co];
    out[((size_t)b * COUT + co) * DP3 + p] = fmaxf(o, 0.f);
}

// ---------------- conv4: Cin=128, Din=4 -> conv 2^3 -> pool 1; wave per (b,co) ----------------
__global__ void conv4_kernel(const float* __restrict__ in, const float* __restrict__ w,
                             const float* __restrict__ bias, float* __restrict__ out) {
    int wid = (int)((blockIdx.x * blockDim.x + threadIdx.x) >> 6);
    int lane = threadIdx.x & 63;
    if (wid >= NB * 256) return;
    int b = wid >> 8, co = wid & 255;
    float acc[8];
#pragma unroll
    for (int i = 0; i < 8; ++i) acc[i] = 0.f;
    for (int half = 0; half < 2; ++half) {
        int ci = lane + half * 64;
        const float* cb = in + ((size_t)b * 128 + ci) * 64;
        float win[64];
        const float4* c4 = (const float4*)cb;
#pragma unroll
        for (int i = 0; i < 16; ++i) {
            float4 v = c4[i];
            win[4 * i + 0] = v.x; win[4 * i + 1] = v.y;
            win[4 * i + 2] = v.z; win[4 * i + 3] = v.w;
        }
        const float* wc = w + ((size_t)co * 128 + ci) * 27;
        float wr[27];
#pragma unroll
        for (int i = 0; i < 27; ++i) wr[i] = wc[i];
#pragma unroll
        for (int kz = 0; kz < 3; ++kz)
#pragma unroll
            for (int ky = 0; ky < 3; ++ky)
#pragma unroll
                for (int kx = 0; kx < 3; ++kx) {
                    float wv = wr[(kz * 3 + ky) * 3 + kx];
#pragma unroll
                    for (int oz = 0; oz < 2; ++oz)
#pragma unroll
                        for (int oy = 0; oy < 2; ++oy)
#pragma unroll
                            for (int ox = 0; ox < 2; ++ox)
                                acc[(oz * 2 + oy) * 2 + ox] =
                                    fmaf(wv, win[((oz + kz) * 4 + (oy + ky)) * 4 + ox + kx],
                                         acc[(oz * 2 + oy) * 2 + ox]);
                }
    }
#pragma unroll
    for (int o = 32; o; o >>= 1)
#pragma unroll
        for (int i = 0; i < 8; ++i) acc[i] += __shfl_xor(acc[i], o);
    if (lane == 0) {
        float m = acc[0];
#pragma unroll
        for (int i = 1; i < 8; ++i) m = fmaxf(m, acc[i]);
        out[(size_t)b * 256 + co] = fmaxf(m + bias[co], 0.f);
    }
}

// ---------------- FC head: (8,256) -> relu(128) -> 29 ----------------
__global__ void head_kernel(const float* __restrict__ v,
                            const float* __restrict__ fw1, const float* __restrict__ fb1,
                            const float* __restrict__ fw2, const float* __restrict__ fb2,
                            float* __restrict__ out) {
    int b = blockIdx.x, t = threadIdx.x;
    __shared__ float sv[256];
    __shared__ float s1[128];
    sv[t] = v[b * 256 + t];
    sv[t + 128] = v[b * 256 + t + 128];
    __syncthreads();
    float acc = fb1[t];
    const float* wr = fw1 + t * 256;
    for (int k = 0; k < 256; ++k) acc = fmaf(wr[k], sv[k], acc);
    s1[t] = fmaxf(acc, 0.f);
    __syncthreads();
    if (t < 29) {
        float a2 = fb2[t];
        const float* w2 = fw2 + t * 128;
        for (int k = 0; k < 128; ++k) a2 = fmaf(w2[k], s1[k], a2);
        out[b * 29 + t] = a2;
    }
}

extern "C" void kernel_launch(void* const* d_in, const int* in_sizes, int n_in,
                              void* d_out, int out_size, void* d_ws, size_t ws_size,
                              hipStream_t stream) {
    const float* x     = (const float*)d_in[0];
    const float* sigma = (const float*)d_in[1];
    const float* w1    = (const float*)d_in[2];
    const float* b1    = (const float*)d_in[3];
    const float* w2    = (const float*)d_in[4];
    const float* b2    = (const float*)d_in[5];
    const float* w3    = (const float*)d_in[6];
    const float* b3    = (const float*)d_in[7];
    const float* w4    = (const float*)d_in[8];
    const float* b4    = (const float*)d_in[9];
    const float* fw1   = (const float*)d_in[10];
    const float* fb1   = (const float*)d_in[11];
    const float* fw2   = (const float*)d_in[12];
    const float* fb2   = (const float*)d_in[13];
    float* out = (float*)d_out;

    float* A  = (float*)d_ws;          // 6,000,000 floats
    float* Bf = A + NVOX;              // 6,000,000 floats
    float* g  = Bf + NVOX;             // 306
    float* gs = g + NE * KK;           // 306
    float* mx = gs + NE * KK;          // 1

    taps_kernel<<<1, 512, 0, stream>>>(sigma, g, gs, mx);

    int nblk = (int)((NVOX + 255) / 256);
    blur_pass<1>          <<<nblk, 256, 0, stream>>>(x,  A,  g);
    blur_pass<DIMX>       <<<nblk, 256, 0, stream>>>(A,  Bf, g);
    blur_pass<DIMX*DIMX>  <<<nblk, 256, 0, stream>>>(Bf, A,  gs);

    max_reduce<<<2048, 256, 0, stream>>>(A, mx);

    // conv1: (8,6,50^3) -> (8,32,24^3), with /max folded in
    conv_pool_relu<6, 50, 24, true><<<dim3(54, 32, 8), 256, 0, stream>>>(A, w1, b1, mx, Bf, 32);
    // conv2: (8,32,24^3) -> (8,64,11^3)
    conv_pool_relu<32, 24, 11, false><<<dim3(6, 64, 8), 256, 0, stream>>>(Bf, w2, b2, nullptr, A, 64);
    // conv3: (8,64,11^3) -> (8,128,4^3)
    conv_pool_relu<64, 11, 4, false><<<dim3(1, 128, 8), 64, 0, stream>>>(A, w3, b3, nullptr, Bf, 128);
    // conv4: (8,128,4^3) -> (8,256)
    conv4_kernel<<<512, 256, 0, stream>>>(Bf, w4, b4, A);
    // head: (8,256) -> (8,29)
    head_kernel<<<8, 128, 0, stream>>>(A, fw1, fb1, fw2, fb2, out);
}

// Round 2
// 757.051 us; speedup vs baseline: 1.8793x; 1.8793x over previous
//
#include <hip/hip_runtime.h>
#include <math.h>

#define DIMX 50
#define KK   51
#define NE   6
#define NB   8
#define NVOX ((size_t)NB * NE * DIMX * DIMX * DIMX)  // 6,000,000

// ---------------- taps: per-element 1D Gaussian + global-sum scale ----------------
__global__ void taps_kernel(const float* __restrict__ sigma,
                            float* __restrict__ g,   // E*51 raw 1D gaussian
                            float* __restrict__ gs,  // E*51 scaled (a_e/S folded in)
                            float* __restrict__ maxval) {
    __shared__ float sg[NE * KK];
    __shared__ float ssum[NE];
    int t = threadIdx.x;
    if (t == 0) *maxval = 0.f;
    if (t < NE * KK) {
        int e = t / KK, i = t % KK;
        float d = (float)i - 25.0f;
        float var = sigma[e] * sigma[e];
        float val = expf(-d * d / (2.f * var));
        sg[t] = val;
        g[t] = val;
    }
    __syncthreads();
    if (t < NE) {
        float s = 0.f;
        for (int i = 0; i < KK; ++i) s += sg[t * KK + i];
        ssum[t] = s;
    }
    __syncthreads();
    if (t < NE * KK) {
        int e = t / KK;
        float S = 0.f;
        for (int e2 = 0; e2 < NE; ++e2) {
            float var2 = sigma[e2] * sigma[e2];
            float a2 = 1.f / (2.f * (float)M_PI * var2);
            float se = ssum[e2];
            S += a2 * se * se * se;
        }
        float var = sigma[e] * sigma[e];
        float a = 1.f / (2.f * (float)M_PI * var);
        gs[t] = sg[t] * (a / S);
    }
}

// ---------------- separable blur pass (zero padding 25), full unroll + predicated loads ----------------
template <int STRIDE>
__global__ void blur_pass(const float* __restrict__ in, float* __restrict__ out,
                          const float* __restrict__ taps) {
    __shared__ float st[NE * KK];
    for (int i = threadIdx.x; i < NE * KK; i += blockDim.x) st[i] = taps[i];
    __syncthreads();
    size_t idx = (size_t)blockIdx.x * blockDim.x + threadIdx.x;
    if (idx >= NVOX) return;
    int w = (int)(idx % DIMX);
    int h = (int)((idx / DIMX) % DIMX);
    int d = (int)((idx / (DIMX * DIMX)) % DIMX);
    int e = (int)((idx / (DIMX * DIMX * DIMX)) % NE);
    int pos = (STRIDE == 1) ? w : (STRIDE == DIMX ? h : d);
    const float* tp = &st[e * KK];
    const float* rowbase = in + (long)idx - (long)pos * STRIDE;
    float acc = 0.f;
#pragma unroll
    for (int j = 0; j < KK; ++j) {
        int c = pos + j - 25;
        float v = ((unsigned)c < DIMX) ? rowbase[(long)c * STRIDE] : 0.f;
        acc = fmaf(tp[j], v, acc);
    }
    out[idx] = acc;
}

// ---------------- global max (all values >= 0) ----------------
__global__ void max_reduce(const float* __restrict__ in, float* __restrict__ maxval) {
    size_t stride = (size_t)gridDim.x * blockDim.x;
    float m = 0.f;
    for (size_t i = (size_t)blockIdx.x * blockDim.x + threadIdx.x; i < NVOX; i += stride)
        m = fmaxf(m, in[i]);
    for (int o = 32; o; o >>= 1) m = fmaxf(m, __shfl_xor(m, o));
    if ((threadIdx.x & 63) == 0) atomicMax((int*)maxval, __float_as_int(m));
}

// ---------------- tiled fused conv3x3x3(VALID) [+pool2+bias+relu | partial store] ----------------
// Block: 4x4x4 pooled tile x 16 output channels. 256 threads = 64 voxels x 4 co-sets.
// Each thread: 4 co x 8 conv voxels in registers. Per-ci double-buffered LDS staging
// (window 10x10x12-pad + 16x27 weights) with issue-early/commit-late overlap.
template <int CIN, int CINTOT, int DIN, int DP, bool DIV, bool PARTIAL>
__global__ __launch_bounds__(256, 2)
void conv_tile(const float* __restrict__ in, const float* __restrict__ w,
               const float* __restrict__ bias, const float* __restrict__ maxval,
               float* __restrict__ out, int COUT) {
    constexpr int NT  = (DP + 3) / 4;
    constexpr int NT3 = NT * NT * NT;
    constexpr int WZ = 10, WY = 10, WXP = 12;
    constexpr int WSZ = WZ * WY * WXP;   // 1200
    constexpr int WTS = 16 * 27;         // 432
    constexpr int STG = WSZ + WTS;       // 1632
    constexpr int NS  = (STG + 255) / 256;  // 7
    __shared__ float swin[2][WSZ];
    __shared__ float swts[2][WTS];

    const int t    = threadIdx.x;
    const int vox  = t & 63;
    const int cset = t >> 6;                  // wave-uniform
    const int px = vox & 3, py = (vox >> 2) & 3, pz = vox >> 4;

    const int tile  = blockIdx.x % NT3;
    const int chunk = blockIdx.x / NT3;       // 0 unless PARTIAL
    const int tx = tile % NT, ty = (tile / NT) % NT, tz = tile / (NT * NT);
    const int b   = blockIdx.z;
    const int co0 = blockIdx.y * 16 + cset * 4;
    const int ci_base = chunk * CIN;

    const float* ib = in + ((size_t)b * CINTOT + ci_base) * (DIN * DIN * DIN);
    const float* wb = w + (size_t)(blockIdx.y * 16) * CINTOT * 27 + (size_t)ci_base * 27;

    const int ox0 = 8 * tx, oy0 = 8 * ty, oz0 = 8 * tz;

    float sreg[NS];
    auto issue = [&](int ci) {
#pragma unroll
        for (int s = 0; s < NS; ++s) {
            int j = t + 256 * s;
            if (j < WSZ) {
                int z = j / (WY * WXP); int r = j % (WY * WXP);
                int y = r / WXP;        int x = r % WXP;
                int gz = oz0 + z; if (gz > DIN - 1) gz = DIN - 1;
                int gy = oy0 + y; if (gy > DIN - 1) gy = DIN - 1;
                int gx = ox0 + x; if (gx > DIN - 1) gx = DIN - 1;
                sreg[s] = ib[(size_t)ci * (DIN * DIN * DIN) + (gz * DIN + gy) * DIN + gx];
            } else if (j < STG) {
                int wi = j - WSZ; int cc = wi / 27; int k = wi % 27;
                sreg[s] = wb[((size_t)cc * CINTOT + ci) * 27 + k];
            }
        }
    };
    auto commit = [&](int buf) {
#pragma unroll
        for (int s = 0; s < NS; ++s) {
            int j = t + 256 * s;
            if (j < WSZ) swin[buf][j] = sreg[s];
            else if (j < STG) swts[buf][j - WSZ] = sreg[s];
        }
    };

    float acc[4][8];
#pragma unroll
    for (int c = 0; c < 4; ++c)
#pragma unroll
        for (int i = 0; i < 8; ++i) acc[c][i] = 0.f;

    issue(0); commit(0); __syncthreads();

    for (int ci = 0; ci < CIN; ++ci) {
        const int cur = ci & 1;
        if (ci + 1 < CIN) issue(ci + 1);

        float win[4][4][4];
#pragma unroll
        for (int dz = 0; dz < 4; ++dz)
#pragma unroll
            for (int dy = 0; dy < 4; ++dy) {
                int base = ((2 * pz + dz) * WY + (2 * py + dy)) * WXP + 2 * px;
                float2 v0 = *(const float2*)&swin[cur][base];
                float2 v1 = *(const float2*)&swin[cur][base + 2];
                win[dz][dy][0] = v0.x; win[dz][dy][1] = v0.y;
                win[dz][dy][2] = v1.x; win[dz][dy][3] = v1.y;
            }
#pragma unroll
        for (int kz = 0; kz < 3; ++kz)
#pragma unroll
            for (int ky = 0; ky < 3; ++ky)
#pragma unroll
                for (int kx = 0; kx < 3; ++kx) {
                    const int k = (kz * 3 + ky) * 3 + kx;
#pragma unroll
                    for (int c = 0; c < 4; ++c) {
                        float wv = swts[cur][(cset * 4 + c) * 27 + k];
#pragma unroll
                        for (int oz = 0; oz < 2; ++oz)
#pragma unroll
                            for (int oy = 0; oy < 2; ++oy)
#pragma unroll
                                for (int ox = 0; ox < 2; ++ox)
                                    acc[c][(oz * 2 + oy) * 2 + ox] =
                                        fmaf(wv, win[oz + kz][oy + ky][ox + kx],
                                             acc[c][(oz * 2 + oy) * 2 + ox]);
                    }
                }
        if (ci + 1 < CIN) commit((ci + 1) & 1);
        __syncthreads();
    }

    if constexpr (PARTIAL) {
        // store pre-pool conv partials: part[((chunk*NB+b)*COUT+co)*512 + vox*8 + i]
#pragma unroll
        for (int c = 0; c < 4; ++c) {
            size_t base = (((size_t)chunk * NB + b) * (size_t)COUT + (co0 + c)) * 512 + (size_t)vox * 8;
#pragma unroll
            for (int i = 0; i < 8; ++i) out[base + i] = acc[c][i];
        }
    } else {
        const int qx = tx * 4 + px, qy = ty * 4 + py, qz = tz * 4 + pz;
        if (qx < DP && qy < DP && qz < DP) {
            float mv = DIV ? *maxval : 1.f;
#pragma unroll
            for (int c = 0; c < 4; ++c) {
                float m = acc[c][0];
#pragma unroll
                for (int i = 1; i < 8; ++i) m = fmaxf(m, acc[c][i]);
                float o = DIV ? (m / mv + bias[co0 + c]) : (m + bias[co0 + c]);
                out[((size_t)b * COUT + (co0 + c)) * (DP * DP * DP) + (qz * DP + qy) * DP + qx] =
                    fmaxf(o, 0.f);
            }
        }
    }
}

// ---------------- conv3 chunk-reduce + pool + bias + relu ----------------
__global__ void pool3_kernel(const float* __restrict__ part, const float* __restrict__ bias,
                             float* __restrict__ out) {
    int idx = blockIdx.x * 256 + threadIdx.x;  // 8*128*64
    if (idx >= NB * 128 * 64) return;
    int vox = idx & 63;
    int co  = (idx >> 6) & 127;
    int b   = idx >> 13;
    float s[8];
#pragma unroll
    for (int i = 0; i < 8; ++i) s[i] = 0.f;
    for (int ch = 0; ch < 4; ++ch) {
        const float* p = part + (((size_t)ch * NB + b) * 128 + co) * 512 + (size_t)vox * 8;
#pragma unroll
        for (int i = 0; i < 8; ++i) s[i] += p[i];
    }
    float m = s[0];
#pragma unroll
    for (int i = 1; i < 8; ++i) m = fmaxf(m, s[i]);
    out[((size_t)b * 128 + co) * 64 + vox] = fmaxf(m + bias[co], 0.f);
}

// ---------------- conv4: Cin=128, Din=4 -> conv 2^3 -> pool 1; wave per (b,co) ----------------
__global__ void conv4_kernel(const float* __restrict__ in, const float* __restrict__ w,
                             const float* __restrict__ bias, float* __restrict__ out) {
    int wid = (int)((blockIdx.x * blockDim.x + threadIdx.x) >> 6);
    int lane = threadIdx.x & 63;
    if (wid >= NB * 256) return;
    int b = wid >> 8, co = wid & 255;
    float acc[8];
#pragma unroll
    for (int i = 0; i < 8; ++i) acc[i] = 0.f;
    for (int half = 0; half < 2; ++half) {
        int ci = lane + half * 64;
        const float* cb = in + ((size_t)b * 128 + ci) * 64;
        float win[64];
        const float4* c4 = (const float4*)cb;
#pragma unroll
        for (int i = 0; i < 16; ++i) {
            float4 v = c4[i];
            win[4 * i + 0] = v.x; win[4 * i + 1] = v.y;
            win[4 * i + 2] = v.z; win[4 * i + 3] = v.w;
        }
        const float* wc = w + ((size_t)co * 128 + ci) * 27;
        float wr[27];
#pragma unroll
        for (int i = 0; i < 27; ++i) wr[i] = wc[i];
#pragma unroll
        for (int kz = 0; kz < 3; ++kz)
#pragma unroll
            for (int ky = 0; ky < 3; ++ky)
#pragma unroll
                for (int kx = 0; kx < 3; ++kx) {
                    float wv = wr[(kz * 3 + ky) * 3 + kx];
#pragma unroll
                    for (int oz = 0; oz < 2; ++oz)
#pragma unroll
                        for (int oy = 0; oy < 2; ++oy)
#pragma unroll
                            for (int ox = 0; ox < 2; ++ox)
                                acc[(oz * 2 + oy) * 2 + ox] =
                                    fmaf(wv, win[((oz + kz) * 4 + (oy + ky)) * 4 + ox + kx],
                                         acc[(oz * 2 + oy) * 2 + ox]);
                }
    }
#pragma unroll
    for (int o = 32; o; o >>= 1)
#pragma unroll
        for (int i = 0; i < 8; ++i) acc[i] += __shfl_xor(acc[i], o);
    if (lane == 0) {
        float m = acc[0];
#pragma unroll
        for (int i = 1; i < 8; ++i) m = fmaxf(m, acc[i]);
        out[(size_t)b * 256 + co] = fmaxf(m + bias[co], 0.f);
    }
}

// ---------------- FC head: (8,256) -> relu(128) -> 29 ----------------
__global__ void head_kernel(const float* __restrict__ v,
                            const float* __restrict__ fw1, const float* __restrict__ fb1,
                            const float* __restrict__ fw2, const float* __restrict__ fb2,
                            float* __restrict__ out) {
    int b = blockIdx.x, t = threadIdx.x;
    __shared__ float sv[256];
    __shared__ float s1[128];
    sv[t] = v[b * 256 + t];
    sv[t + 128] = v[b * 256 + t + 128];
    __syncthreads();
    float acc = fb1[t];
    const float* wr = fw1 + t * 256;
    for (int k = 0; k < 256; ++k) acc = fmaf(wr[k], sv[k], acc);
    s1[t] = fmaxf(acc, 0.f);
    __syncthreads();
    if (t < 29) {
        float a2 = fb2[t];
        const float* w2 = fw2 + t * 128;
        for (int k = 0; k < 128; ++k) a2 = fmaf(w2[k], s1[k], a2);
        out[b * 29 + t] = a2;
    }
}

extern "C" void kernel_launch(void* const* d_in, const int* in_sizes, int n_in,
                              void* d_out, int out_size, void* d_ws, size_t ws_size,
                              hipStream_t stream) {
    const float* x     = (const float*)d_in[0];
    const float* sigma = (const float*)d_in[1];
    const float* w1    = (const float*)d_in[2];
    const float* b1    = (const float*)d_in[3];
    const float* w2    = (const float*)d_in[4];
    const float* b2    = (const float*)d_in[5];
    const float* w3    = (const float*)d_in[6];
    const float* b3    = (const float*)d_in[7];
    const float* w4    = (const float*)d_in[8];
    const float* b4    = (const float*)d_in[9];
    const float* fw1   = (const float*)d_in[10];
    const float* fb1   = (const float*)d_in[11];
    const float* fw2   = (const float*)d_in[12];
    const float* fb2   = (const float*)d_in[13];
    float* out = (float*)d_out;

    float* A  = (float*)d_ws;          // 6,000,000 floats
    float* Bf = A + NVOX;              // 6,000,000 floats
    float* g  = Bf + NVOX;             // 306
    float* gs = g + NE * KK;           // 306
    float* mx = gs + NE * KK;          // 1

    taps_kernel<<<1, 512, 0, stream>>>(sigma, g, gs, mx);

    int nblk = (int)((NVOX + 255) / 256);
    blur_pass<1>          <<<nblk, 256, 0, stream>>>(x,  A,  g);
    blur_pass<DIMX>       <<<nblk, 256, 0, stream>>>(A,  Bf, g);
    blur_pass<DIMX*DIMX>  <<<nblk, 256, 0, stream>>>(Bf, A,  gs);

    max_reduce<<<2048, 256, 0, stream>>>(A, mx);

    // conv1: (8,6,50^3) -> (8,32,24^3), /max folded into epilogue
    conv_tile<6, 6, 50, 24, true, false><<<dim3(216, 2, 8), 256, 0, stream>>>(A, w1, b1, mx, Bf, 32);
    // conv2: (8,32,24^3) -> (8,64,11^3)
    conv_tile<32, 32, 24, 11, false, false><<<dim3(27, 4, 8), 256, 0, stream>>>(Bf, w2, b2, nullptr, A, 64);
    // conv3: (8,64,11^3) -> partials over 4 ci-chunks (into Bf region, conv2 input dead)
    float* part = Bf;                                  // 4*8*128*512 = 2,097,152 floats
    float* pooled3 = Bf + 4 * NB * 128 * 512;          // 8*128*64 floats
    conv_tile<16, 64, 11, 4, false, true><<<dim3(4, 8, 8), 256, 0, stream>>>(A, w3, b3, nullptr, part, 128);
    pool3_kernel<<<256, 256, 0, stream>>>(part, b3, pooled3);
    // conv4: (8,128,4^3) -> (8,256)  (write into A; conv3 input dead)
    float* v4 = A;
    conv4_kernel<<<512, 256, 0, stream>>>(pooled3, w4, b4, v4);
    // head
    head_kernel<<<8, 128, 0, stream>>>(v4, fw1, fb1, fw2, fb2, out);
}

// Round 3
// 755.960 us; speedup vs baseline: 1.8820x; 1.0014x over previous
//
#include <hip/hip_runtime.h>
#include <math.h>

#define DIMX 50
#define KK   51
#define NE   6
#define NB   8
#define NVOX ((size_t)NB * NE * DIMX * DIMX * DIMX)  // 6,000,000

// ---------------- taps: per-element 1D Gaussian + global-sum scale ----------------
__global__ void taps_kernel(const float* __restrict__ sigma,
                            float* __restrict__ g,   // E*51 raw 1D gaussian
                            float* __restrict__ gs,  // E*51 scaled (a_e/S folded in)
                            float* __restrict__ maxval) {
    __shared__ float sg[NE * KK];
    __shared__ float ssum[NE];
    int t = threadIdx.x;
    if (t == 0) *maxval = 0.f;
    if (t < NE * KK) {
        int e = t / KK, i = t % KK;
        float d = (float)i - 25.0f;
        float var = sigma[e] * sigma[e];
        float val = expf(-d * d / (2.f * var));
        sg[t] = val;
        g[t] = val;
    }
    __syncthreads();
    if (t < NE) {
        float s = 0.f;
        for (int i = 0; i < KK; ++i) s += sg[t * KK + i];
        ssum[t] = s;
    }
    __syncthreads();
    if (t < NE * KK) {
        int e = t / KK;
        float S = 0.f;
        for (int e2 = 0; e2 < NE; ++e2) {
            float var2 = sigma[e2] * sigma[e2];
            float a2 = 1.f / (2.f * (float)M_PI * var2);
            float se = ssum[e2];
            S += a2 * se * se * se;
        }
        float var = sigma[e] * sigma[e];
        float a = 1.f / (2.f * (float)M_PI * var);
        gs[t] = sg[t] * (a / S);
    }
}

// ---------------- separable blur pass (zero padding 25), full unroll + predicated loads ----------------
template <int STRIDE>
__global__ void blur_pass(const float* __restrict__ in, float* __restrict__ out,
                          const float* __restrict__ taps) {
    __shared__ float st[NE * KK];
    for (int i = threadIdx.x; i < NE * KK; i += blockDim.x) st[i] = taps[i];
    __syncthreads();
    size_t idx = (size_t)blockIdx.x * blockDim.x + threadIdx.x;
    if (idx >= NVOX) return;
    int w = (int)(idx % DIMX);
    int h = (int)((idx / DIMX) % DIMX);
    int d = (int)((idx / (DIMX * DIMX)) % DIMX);
    int e = (int)((idx / (DIMX * DIMX * DIMX)) % NE);
    int pos = (STRIDE == 1) ? w : (STRIDE == DIMX ? h : d);
    const float* tp = &st[e * KK];
    const float* rowbase = in + (long)idx - (long)pos * STRIDE;
    float acc = 0.f;
#pragma unroll
    for (int j = 0; j < KK; ++j) {
        int c = pos + j - 25;
        float v = ((unsigned)c < DIMX) ? rowbase[(long)c * STRIDE] : 0.f;
        acc = fmaf(tp[j], v, acc);
    }
    out[idx] = acc;
}

// ---------------- global max (all values >= 0) ----------------
__global__ void max_reduce(const float* __restrict__ in, float* __restrict__ maxval) {
    size_t stride = (size_t)gridDim.x * blockDim.x;
    float m = 0.f;
    for (size_t i = (size_t)blockIdx.x * blockDim.x + threadIdx.x; i < NVOX; i += stride)
        m = fmaxf(m, in[i]);
    for (int o = 32; o; o >>= 1) m = fmaxf(m, __shfl_xor(m, o));
    if ((threadIdx.x & 63) == 0) atomicMax((int*)maxval, __float_as_int(m));
}

// ---------------- tiled fused conv3x3x3(VALID) [+pool2+bias+relu | partial store] ----------------
// Block: 4x4x4 pooled tile x 16 output channels. 256 threads = 64 voxels x 4 co-sets.
// Window staged in double-buffered LDS (issue-early/commit-late); weights read via
// wave-uniform (readfirstlane-forced) scalar loads -> SGPRs, consumed by FMA directly.
template <int CIN, int CINTOT, int DIN, int DP, bool DIV, bool PARTIAL>
__global__ __launch_bounds__(256, 4)
void conv_tile(const float* __restrict__ in, const float* __restrict__ w,
               const float* __restrict__ bias, const float* __restrict__ maxval,
               float* __restrict__ out, int COUT) {
    constexpr int NT  = (DP + 3) / 4;
    constexpr int NT3 = NT * NT * NT;
    constexpr int WZ = 10, WY = 10, WXP = 12;
    constexpr int WSZ = WZ * WY * WXP;   // 1200
    constexpr int NS  = (WSZ + 255) / 256;  // 5
    __shared__ float swin[2][WSZ];

    const int t    = threadIdx.x;
    const int vox  = t & 63;
    const int cset = t >> 6;                  // wave-uniform
    const int csetU = __builtin_amdgcn_readfirstlane(cset);
    const int px = vox & 3, py = (vox >> 2) & 3, pz = vox >> 4;

    const int tile  = blockIdx.x % NT3;
    const int chunk = blockIdx.x / NT3;       // 0 unless PARTIAL
    const int tx = tile % NT, ty = (tile / NT) % NT, tz = tile / (NT * NT);
    const int b   = blockIdx.z;
    const int co0U = blockIdx.y * 16 + csetU * 4;   // uniform
    const int ci_base = chunk * CIN;

    const float* ib = in + ((size_t)b * CINTOT + ci_base) * (DIN * DIN * DIN);
    const float* wb = w + ((size_t)co0U * CINTOT + ci_base) * 27;  // uniform base

    const int ox0 = 8 * tx, oy0 = 8 * ty, oz0 = 8 * tz;

    float sreg[NS];
    auto issue = [&](int ci) {
#pragma unroll
        for (int s = 0; s < NS; ++s) {
            int j = t + 256 * s;
            if (j < WSZ) {
                int z = j / (WY * WXP); int r = j % (WY * WXP);
                int y = r / WXP;        int x = r % WXP;
                int gz = oz0 + z; if (gz > DIN - 1) gz = DIN - 1;
                int gy = oy0 + y; if (gy > DIN - 1) gy = DIN - 1;
                int gx = ox0 + x; if (gx > DIN - 1) gx = DIN - 1;
                sreg[s] = ib[(size_t)ci * (DIN * DIN * DIN) + (gz * DIN + gy) * DIN + gx];
            }
        }
    };
    auto commit = [&](int buf) {
#pragma unroll
        for (int s = 0; s < NS; ++s) {
            int j = t + 256 * s;
            if (j < WSZ) swin[buf][j] = sreg[s];
        }
    };

    float acc[4][8];
#pragma unroll
    for (int c = 0; c < 4; ++c)
#pragma unroll
        for (int i = 0; i < 8; ++i) acc[c][i] = 0.f;

    issue(0); commit(0); __syncthreads();

    for (int ci = 0; ci < CIN; ++ci) {
        const int cur = ci & 1;
        if (ci + 1 < CIN) issue(ci + 1);

        float win[4][4][4];
#pragma unroll
        for (int dz = 0; dz < 4; ++dz)
#pragma unroll
            for (int dy = 0; dy < 4; ++dy) {
                int base = ((2 * pz + dz) * WY + (2 * py + dy)) * WXP + 2 * px;
                float2 v0 = *(const float2*)&swin[cur][base];
                float2 v1 = *(const float2*)&swin[cur][base + 2];
                win[dz][dy][0] = v0.x; win[dz][dy][1] = v0.y;
                win[dz][dy][2] = v1.x; win[dz][dy][3] = v1.y;
            }
#pragma unroll
        for (int c = 0; c < 4; ++c) {
            // wave-uniform scalar loads: 27 weights for (co0U+c, ci_base+ci)
            const float* wc = wb + ((size_t)c * CINTOT + ci) * 27;
            float wt[27];
#pragma unroll
            for (int k = 0; k < 27; ++k) wt[k] = wc[k];
#pragma unroll
            for (int kz = 0; kz < 3; ++kz)
#pragma unroll
                for (int ky = 0; ky < 3; ++ky)
#pragma unroll
                    for (int kx = 0; kx < 3; ++kx) {
                        float wv = wt[(kz * 3 + ky) * 3 + kx];
#pragma unroll
                        for (int oz = 0; oz < 2; ++oz)
#pragma unroll
                            for (int oy = 0; oy < 2; ++oy)
#pragma unroll
                                for (int ox = 0; ox < 2; ++ox)
                                    acc[c][(oz * 2 + oy) * 2 + ox] =
                                        fmaf(wv, win[oz + kz][oy + ky][ox + kx],
                                             acc[c][(oz * 2 + oy) * 2 + ox]);
                    }
        }
        if (ci + 1 < CIN) commit((ci + 1) & 1);
        __syncthreads();
    }

    if constexpr (PARTIAL) {
#pragma unroll
        for (int c = 0; c < 4; ++c) {
            size_t base = (((size_t)chunk * NB + b) * (size_t)COUT + (co0U + c)) * 512 + (size_t)vox * 8;
#pragma unroll
            for (int i = 0; i < 8; ++i) out[base + i] = acc[c][i];
        }
    } else {
        const int qx = tx * 4 + px, qy = ty * 4 + py, qz = tz * 4 + pz;
        if (qx < DP && qy < DP && qz < DP) {
            float mv = DIV ? *maxval : 1.f;
#pragma unroll
            for (int c = 0; c < 4; ++c) {
                float m = acc[c][0];
#pragma unroll
                for (int i = 1; i < 8; ++i) m = fmaxf(m, acc[c][i]);
                float o = DIV ? (m / mv + bias[co0U + c]) : (m + bias[co0U + c]);
                out[((size_t)b * COUT + (co0U + c)) * (DP * DP * DP) + (qz * DP + qy) * DP + qx] =
                    fmaxf(o, 0.f);
            }
        }
    }
}

// ---------------- conv3 chunk-reduce + pool + bias + relu ----------------
template <int NCH>
__global__ void pool3_kernel(const float* __restrict__ part, const float* __restrict__ bias,
                             float* __restrict__ out) {
    int idx = blockIdx.x * 256 + threadIdx.x;  // 8*128*64
    if (idx >= NB * 128 * 64) return;
    int vox = idx & 63;
    int co  = (idx >> 6) & 127;
    int b   = idx >> 13;
    float s[8];
#pragma unroll
    for (int i = 0; i < 8; ++i) s[i] = 0.f;
#pragma unroll
    for (int ch = 0; ch < NCH; ++ch) {
        const float* p = part + (((size_t)ch * NB + b) * 128 + co) * 512 + (size_t)vox * 8;
#pragma unroll
        for (int i = 0; i < 8; ++i) s[i] += p[i];
    }
    float m = s[0];
#pragma unroll
    for (int i = 1; i < 8; ++i) m = fmaxf(m, s[i]);
    out[((size_t)b * 128 + co) * 64 + vox] = fmaxf(m + bias[co], 0.f);
}

// ---------------- conv4: Cin=128, Din=4 -> conv 2^3 -> pool 1; wave per (b,co) ----------------
__global__ void conv4_kernel(const float* __restrict__ in, const float* __restrict__ w,
                             const float* __restrict__ bias, float* __restrict__ out) {
    int wid = (int)((blockIdx.x * blockDim.x + threadIdx.x) >> 6);
    int lane = threadIdx.x & 63;
    if (wid >= NB * 256) return;
    int b = wid >> 8, co = wid & 255;
    float acc[8];
#pragma unroll
    for (int i = 0; i < 8; ++i) acc[i] = 0.f;
    for (int half = 0; half < 2; ++half) {
        int ci = lane + half * 64;
        const float* cb = in + ((size_t)b * 128 + ci) * 64;
        float win[64];
        const float4* c4 = (const float4*)cb;
#pragma unroll
        for (int i = 0; i < 16; ++i) {
            float4 v = c4[i];
            win[4 * i + 0] = v.x; win[4 * i + 1] = v.y;
            win[4 * i + 2] = v.z; win[4 * i + 3] = v.w;
        }
        const float* wc = w + ((size_t)co * 128 + ci) * 27;
        float wr[27];
#pragma unroll
        for (int i = 0; i < 27; ++i) wr[i] = wc[i];
#pragma unroll
        for (int kz = 0; kz < 3; ++kz)
#pragma unroll
            for (int ky = 0; ky < 3; ++ky)
#pragma unroll
                for (int kx = 0; kx < 3; ++kx) {
                    float wv = wr[(kz * 3 + ky) * 3 + kx];
#pragma unroll
                    for (int oz = 0; oz < 2; ++oz)
#pragma unroll
                        for (int oy = 0; oy < 2; ++oy)
#pragma unroll
                            for (int ox = 0; ox < 2; ++ox)
                                acc[(oz * 2 + oy) * 2 + ox] =
                                    fmaf(wv, win[((oz + kz) * 4 + (oy + ky)) * 4 + ox + kx],
                                         acc[(oz * 2 + oy) * 2 + ox]);
                }
    }
#pragma unroll
    for (int o = 32; o; o >>= 1)
#pragma unroll
        for (int i = 0; i < 8; ++i) acc[i] += __shfl_xor(acc[i], o);
    if (lane == 0) {
        float m = acc[0];
#pragma unroll
        for (int i = 1; i < 8; ++i) m = fmaxf(m, acc[i]);
        out[(size_t)b * 256 + co] = fmaxf(m + bias[co], 0.f);
    }
}

// ---------------- FC head: (8,256) -> relu(128) -> 29 ----------------
__global__ void head_kernel(const float* __restrict__ v,
                            const float* __restrict__ fw1, const float* __restrict__ fb1,
                            const float* __restrict__ fw2, const float* __restrict__ fb2,
                            float* __restrict__ out) {
    int b = blockIdx.x, t = threadIdx.x;
    __shared__ float sv[256];
    __shared__ float s1[128];
    sv[t] = v[b * 256 + t];
    sv[t + 128] = v[b * 256 + t + 128];
    __syncthreads();
    float acc = fb1[t];
    const float* wr = fw1 + t * 256;
    for (int k = 0; k < 256; ++k) acc = fmaf(wr[k], sv[k], acc);
    s1[t] = fmaxf(acc, 0.f);
    __syncthreads();
    if (t < 29) {
        float a2 = fb2[t];
        const float* w2 = fw2 + t * 128;
        for (int k = 0; k < 128; ++k) a2 = fmaf(w2[k], s1[k], a2);
        out[b * 29 + t] = a2;
    }
}

extern "C" void kernel_launch(void* const* d_in, const int* in_sizes, int n_in,
                              void* d_out, int out_size, void* d_ws, size_t ws_size,
                              hipStream_t stream) {
    const float* x     = (const float*)d_in[0];
    const float* sigma = (const float*)d_in[1];
    const float* w1    = (const float*)d_in[2];
    const float* b1    = (const float*)d_in[3];
    const float* w2    = (const float*)d_in[4];
    const float* b2    = (const float*)d_in[5];
    const float* w3    = (const float*)d_in[6];
    const float* b3    = (const float*)d_in[7];
    const float* w4    = (const float*)d_in[8];
    const float* b4    = (const float*)d_in[9];
    const float* fw1   = (const float*)d_in[10];
    const float* fb1   = (const float*)d_in[11];
    const float* fw2   = (const float*)d_in[12];
    const float* fb2   = (const float*)d_in[13];
    float* out = (float*)d_out;

    float* A  = (float*)d_ws;          // 6,000,000 floats
    float* Bf = A + NVOX;              // 6,000,000 floats
    float* g  = Bf + NVOX;             // 306
    float* gs = g + NE * KK;           // 306
    float* mx = gs + NE * KK;          // 1

    taps_kernel<<<1, 512, 0, stream>>>(sigma, g, gs, mx);

    int nblk = (int)((NVOX + 255) / 256);
    blur_pass<1>          <<<nblk, 256, 0, stream>>>(x,  A,  g);
    blur_pass<DIMX>       <<<nblk, 256, 0, stream>>>(A,  Bf, g);
    blur_pass<DIMX*DIMX>  <<<nblk, 256, 0, stream>>>(Bf, A,  gs);

    max_reduce<<<2048, 256, 0, stream>>>(A, mx);

    // conv1: (8,6,50^3) -> (8,32,24^3), /max folded into epilogue
    conv_tile<6, 6, 50, 24, true, false><<<dim3(216, 2, 8), 256, 0, stream>>>(A, w1, b1, mx, Bf, 32);
    // conv2: (8,32,24^3) -> (8,64,11^3)
    conv_tile<32, 32, 24, 11, false, false><<<dim3(27, 4, 8), 256, 0, stream>>>(Bf, w2, b2, nullptr, A, 64);
    // conv3: (8,64,11^3) -> partials over 8 ci-chunks (into Bf region, conv2 input dead)
    float* part = Bf;                                  // 8*8*128*512 = 4,194,304 floats
    float* pooled3 = Bf + 8 * NB * 128 * 512;          // 8*128*64 floats
    conv_tile<8, 64, 11, 4, false, true><<<dim3(8, 8, 8), 256, 0, stream>>>(A, w3, b3, nullptr, part, 128);
    pool3_kernel<8><<<256, 256, 0, stream>>>(part, b3, pooled3);
    // conv4: (8,128,4^3) -> (8,256)  (write into A; conv3 input dead)
    float* v4 = A;
    conv4_kernel<<<512, 256, 0, stream>>>(pooled3, w4, b4, v4);
    // head
    head_kernel<<<8, 128, 0, stream>>>(v4, fw1, fb1, fw2, fb2, out);
}